// Round 2
// baseline (861.946 us; speedup 1.0000x reference)
//
#include <hip/hip_runtime.h>

typedef _Float16 f16;
typedef __attribute__((ext_vector_type(8))) _Float16 f16x8;
typedef __attribute__((ext_vector_type(4))) _Float16 f16x4;
typedef __attribute__((ext_vector_type(4))) float f32x4;

// ---- global_load_lds width-16 helper (m97 pattern) ----
typedef const __attribute__((address_space(1))) unsigned int* gas_ptr;
typedef __attribute__((address_space(3))) unsigned int* las_ptr;

__device__ __forceinline__ void gload16(const f16* g, f16* l) {
  __builtin_amdgcn_global_load_lds((gas_ptr)g, (las_ptr)l, 16, 0, 0);
}

// =====================================================================
// Generic MFMA GEMM core: C[m,n] = scale * sum_k A[m,k]*B[n,k] (+bias)
// A: (WM*64 rows) row-major lda, k contiguous; B: (WN*64 rows = out cols)
// row-major ldb, k contiguous. BK=64, 16x16x32 f16 MFMA, fp32 acc.
// kLen must be a multiple of 64. All tile dims divide problem dims.
// =====================================================================
template<int WM, int WN, bool OUT32>
__device__ __forceinline__ void gemm_core(
    const f16* __restrict__ A, int lda,
    const f16* __restrict__ B, int ldb,
    int kLen,
    f16* lsA, f16* lsB,
    float* __restrict__ C32, f16* __restrict__ C16, int ldc,
    float scale, const float* __restrict__ biasC, const float* __restrict__ biasR)
{
  constexpr int T   = WM * WN * 64;      // threads per block
  constexpr int nA  = (WM * 64 * 8) / T; // global_load_lds insts for A tile
  constexpr int nB  = (WN * 64 * 8) / T;
  constexpr int RPI = T / 8;             // rows staged per inst
  const int t    = threadIdx.x;
  const int lane = t & 63;
  const int wave = t >> 6;
  const int wm   = wave / WN;
  const int wn   = wave % WN;

  f32x4 acc[4][4];
  const f32x4 z4 = {0.f, 0.f, 0.f, 0.f};
#pragma unroll
  for (int i = 0; i < 4; ++i)
#pragma unroll
    for (int j = 0; j < 4; ++j) acc[i][j] = z4;

  const int r_ = t >> 3;            // row within staging group
  const int c_ = (t & 7) * 8;       // k offset (f16 units)
  const int ldsOff = (wave << 9);   // wave * 64 lanes * 8 f16

  for (int kt = 0; kt < kLen; kt += 64) {
#pragma unroll
    for (int i = 0; i < nA; ++i) {
      const f16* g = A + (size_t)(i * RPI + r_) * lda + kt + c_;
      gload16(g, lsA + i * (T * 8) + ldsOff);
    }
#pragma unroll
    for (int i = 0; i < nB; ++i) {
      const f16* g = B + (size_t)(i * RPI + r_) * ldb + kt + c_;
      gload16(g, lsB + i * (T * 8) + ldsOff);
    }
    __syncthreads();   // compiler drains vmcnt(0) before s_barrier
#pragma unroll
    for (int ks = 0; ks < 2; ++ks) {
      f16x8 af[4], bf[4];
#pragma unroll
      for (int i = 0; i < 4; ++i)
        af[i] = *(const f16x8*)&lsA[(wm * 64 + i * 16 + (lane & 15)) * 64 + ks * 32 + (lane >> 4) * 8];
#pragma unroll
      for (int j = 0; j < 4; ++j)
        bf[j] = *(const f16x8*)&lsB[(wn * 64 + j * 16 + (lane & 15)) * 64 + ks * 32 + (lane >> 4) * 8];
#pragma unroll
      for (int i = 0; i < 4; ++i)
#pragma unroll
        for (int j = 0; j < 4; ++j)
          acc[i][j] = __builtin_amdgcn_mfma_f32_16x16x32_f16(af[i], bf[j], acc[i][j], 0, 0, 0);
    }
    __syncthreads();
  }

  // epilogue: C/D layout col=lane&15, row=(lane>>4)*4+reg (m89-verified)
  const int lc = lane & 15;
  const int lr = (lane >> 4) * 4;
#pragma unroll
  for (int j = 0; j < 4; ++j) {
    const int col = wn * 64 + j * 16 + lc;
    const float bC = biasC ? biasC[col] : 0.f;
#pragma unroll
    for (int i = 0; i < 4; ++i) {
      const int rbase = wm * 64 + i * 16 + lr;
#pragma unroll
      for (int r = 0; r < 4; ++r) {
        const int row = rbase + r;
        float v = acc[i][j][r] * scale + bC;
        if (biasR) v += biasR[row];
        if (OUT32) C32[(size_t)row * ldc + col] = v;
        else       C16[(size_t)row * ldc + col] = (f16)v;
      }
    }
  }
}

// ---- generic single-GEMM wrapper ----
template<int WM, int WN, bool OUT32>
__global__ __launch_bounds__(WM * WN * 64) void k_gemm(
    const f16* A, int lda, const f16* B, int ldb, int kLen,
    float* C32, f16* C16, int ldc, float scale,
    const float* biasC, const float* biasR)
{
  __shared__ f16 lsA[WM * 64 * 64];
  __shared__ f16 lsB[WN * 64 * 64];
  const size_t rt = blockIdx.y, ct = blockIdx.x;
  gemm_core<WM, WN, OUT32>(
      A + rt * (WM * 64) * (size_t)lda, lda,
      B + ct * (WN * 64) * (size_t)ldb, ldb, kLen,
      lsA, lsB,
      OUT32 ? C32 + rt * (WM * 64) * (size_t)ldc + ct * (WN * 64) : nullptr,
      OUT32 ? nullptr : C16 + rt * (WM * 64) * (size_t)ldc + ct * (WN * 64), ldc,
      scale,
      biasC ? biasC + ct * (WN * 64) : nullptr,
      biasR ? biasR + rt * (WM * 64) : nullptr);
}

// ---- stage 2: Kp = E·Kt_b^T (256x1024), Vp^T = Vt_b·F^T (1024x256), split-K x4 ----
__global__ __launch_bounds__(256) void k_lowrank(
    const f16* __restrict__ EF, const f16* __restrict__ Kt,
    const f16* __restrict__ Vt, float* __restrict__ part)
{
  const int z = blockIdx.z;
  const int b = z & 3;
  const int which = (z >> 2) & 1;
  const int s = z >> 3;               // split-K index, k window = s*1024
  const int tile = blockIdx.x;        // 16 tiles of 128x128
  __shared__ f16 lsA[128 * 64];
  __shared__ f16 lsB[128 * 64];
  const f16* A; const f16* B; float* C; int lda, ldb, ldc;
  if (which == 0) { // Kp: M=256 (r), N=1024 (e')
    const int rt = tile >> 3, ct = tile & 7;
    A = EF + (size_t)s * 1024 + (size_t)rt * 128 * 4096;                 lda = 4096;
    B = Kt + (size_t)b * 4096 + (size_t)s * 1024 + (size_t)ct * 128 * 16384; ldb = 16384;
    C = part + (size_t)(s * 8 + b) * 262144 + (size_t)rt * 128 * 1024 + ct * 128; ldc = 1024;
  } else {          // Vp^T: M=1024 (e'), N=256 (r)
    const int rt = tile >> 1, ct = tile & 1;
    A = Vt + (size_t)b * 4096 + (size_t)s * 1024 + (size_t)rt * 128 * 16384; lda = 16384;
    B = EF + 1048576 + (size_t)s * 1024 + (size_t)ct * 128 * 4096;       ldb = 4096;
    C = part + (size_t)(s * 8 + 4 + b) * 262144 + (size_t)rt * 128 * 256 + ct * 128; ldc = 256;
  }
  gemm_core<2, 2, true>(A, lda, B, ldb, 1024, lsA, lsB, C, nullptr, ldc, 1.f, nullptr, nullptr);
}

// ---- reduce split-K partials -> fp16 ----
__global__ __launch_bounds__(256) void k_reduce(const float* __restrict__ part,
                                                f16* __restrict__ out)
{
  const size_t i = ((size_t)blockIdx.x * 256 + threadIdx.x) * 4;
  const size_t w4b = i >> 18;          // 0..7: [Kp b0..3, Vp b0..3]
  const size_t idx = i & 262143;
  const float4 a = *(const float4*)(part + (0 * 8 + w4b) * 262144 + idx);
  const float4 b = *(const float4*)(part + (1 * 8 + w4b) * 262144 + idx);
  const float4 c = *(const float4*)(part + (2 * 8 + w4b) * 262144 + idx);
  const float4 d = *(const float4*)(part + (3 * 8 + w4b) * 262144 + idx);
  f16x4 o = {(f16)(a.x + b.x + c.x + d.x), (f16)(a.y + b.y + c.y + d.y),
             (f16)(a.z + b.z + c.z + d.z), (f16)(a.w + b.w + c.w + d.w)};
  *(f16x4*)(out + i) = o;
}

// ---- stage 3: scores = Q·Kp^T / 8 -> fp32 (d_out attn region) ----
__global__ __launch_bounds__(256) void k_scores(const f16* __restrict__ Q,
                                                const f16* __restrict__ Kp,
                                                float* __restrict__ S)
{
  __shared__ f16 lsA[128 * 64];
  __shared__ f16 lsB[128 * 64];
  const int bh = blockIdx.z; const int b = bh >> 4; const int h = bh & 15;
  const size_t rt = blockIdx.y, ct = blockIdx.x;
  const f16* A = Q + (size_t)b * 4096 * 1024 + h * 64 + rt * 128 * 1024;
  const f16* B = Kp + (size_t)b * 262144 + h * 64 + ct * 128 * 1024;
  float* C = S + (size_t)bh * 4096 * 256 + rt * 128 * 256 + ct * 128;
  gemm_core<2, 2, true>(A, 1024, B, 1024, 64, lsA, lsB, C, nullptr, 256, 0.125f, nullptr, nullptr);
}

// ---- stage 3.5: fp32 softmax over rows of 256, one wave per row (per batch) ----
__global__ __launch_bounds__(256) void k_softmax(const float* __restrict__ S,
                                                 f16* __restrict__ P)
{
  const int row  = blockIdx.x * 4 + (threadIdx.x >> 6);  // local row within batch
  const int lane = threadIdx.x & 63;
  const float4 v = *(const float4*)(S + (size_t)row * 256 + lane * 4);
  float m = fmaxf(fmaxf(v.x, v.y), fmaxf(v.z, v.w));
#pragma unroll
  for (int o = 32; o; o >>= 1) m = fmaxf(m, __shfl_xor(m, o));
  const float e0 = __expf(v.x - m), e1 = __expf(v.y - m);
  const float e2 = __expf(v.z - m), e3 = __expf(v.w - m);
  float sum = e0 + e1 + e2 + e3;
#pragma unroll
  for (int o = 32; o; o >>= 1) sum += __shfl_xor(sum, o);
  const float inv = 1.f / sum;
  f16x4 p = {(f16)(e0 * inv), (f16)(e1 * inv), (f16)(e2 * inv), (f16)(e3 * inv)};
  *(f16x4*)(P + (size_t)row * 256 + lane * 4) = p;
}

// ---- stage 4: out_pre = P·Vp  (tile 128x64, 2 waves; one batch at a time) ----
__global__ __launch_bounds__(128) void k_pv(const f16* __restrict__ P,
                                            const f16* __restrict__ VpT,
                                            f16* __restrict__ OP, int b)
{
  __shared__ f16 lsA[128 * 64];
  __shared__ f16 lsB[64 * 64];
  const int h = blockIdx.z;           // head
  const size_t rt = blockIdx.y;
  const f16* A = P + ((size_t)h * 4096 + rt * 128) * 256;   // P for this batch
  const f16* B = VpT + (size_t)b * 262144 + (size_t)h * 64 * 256;
  f16* C = OP + (size_t)b * 4096 * 1024 + rt * 128 * 1024 + h * 64;
  gemm_core<2, 1, false>(A, 256, B, 256, 256, lsA, lsB, nullptr, C, 1024, 1.f, nullptr, nullptr);
}

// ---- casts ----
__global__ __launch_bounds__(256) void k_cast_x(const float* __restrict__ x,
                                                f16* __restrict__ d)
{
  const size_t i = ((size_t)blockIdx.x * 256 + threadIdx.x) * 4;
  const float4 v = *(const float4*)(x + i);
  f16x4 o = {(f16)v.x, (f16)v.y, (f16)v.z, (f16)v.w};
  *(f16x4*)(d + i) = o;
}

__global__ __launch_bounds__(256) void k_cast_w(
    const float* w0, const float* w1, const float* w2,
    const float* w3, const float* w4, const float* w5, f16* __restrict__ d)
{
  const size_t i = ((size_t)blockIdx.x * 256 + threadIdx.x) * 4;
  const int seg = (int)(i >> 20);
  const float* s = (seg == 0) ? w0 : (seg == 1) ? w1 : (seg == 2) ? w2
                 : (seg == 3) ? w3 : (seg == 4) ? w4 : w5;
  const float4 v = *(const float4*)(s + (i & 1048575));
  f16x4 o = {(f16)v.x, (f16)v.y, (f16)v.z, (f16)v.w};
  *(f16x4*)(d + i) = o;
}

// =====================================================================
// Workspace layout (151 MB, regions time-aliased):
//  R0 @0        (33.5MB): Xf16 -> split-K partials(f32, 32MB) -> P16 (ONE batch: 33.5MB)
//  R1 @33.5MB   (33.5MB): Q16 -> out_pre16
//  R2 @67MB     (33.5MB): Kt16  (1024 x 16384)
//  R3 @100.6MB  (33.5MB): Vt16  (1024 x 16384)
//  R4 @134.2MB  ( 8.4MB): Wq/Wk/Wv/Wo f16
//  R5 @142.6MB  ( 4.2MB): E,F f16
//  R6 @146.8MB  ( 4.2MB): Kp16 (b,256,1024) + Vp_t16 (b,1024,256)
// P (134MB total) is processed one batch at a time so it fits R0.
// =====================================================================
extern "C" void kernel_launch(void* const* d_in, const int* in_sizes, int n_in,
                              void* d_out, int out_size, void* d_ws, size_t ws_size,
                              hipStream_t stream) {
  const float* x  = (const float*)d_in[0];
  const float* Wq = (const float*)d_in[1];
  const float* bq = (const float*)d_in[2];
  const float* Wk = (const float*)d_in[3];
  const float* bk = (const float*)d_in[4];
  const float* Wv = (const float*)d_in[5];
  const float* bv = (const float*)d_in[6];
  const float* E  = (const float*)d_in[7];
  const float* F  = (const float*)d_in[8];
  const float* Wo = (const float*)d_in[9];
  const float* bo = (const float*)d_in[10];

  float* out = (float*)d_out;           // 16,777,216 f32
  float* S   = out + 16777216;          // attn_score region, 67,108,864 f32

  char* w = (char*)d_ws;
  f16*   Xf   = (f16*)w;                          // R0
  float* part = (float*)w;                        // R0 (after X dead)
  f16*   Pf   = (f16*)w;                          // R0 (after part dead; one batch)
  f16*   Qf   = (f16*)(w + 33554432);             // R1
  f16*   OPf  = (f16*)(w + 33554432);             // R1 (after Q dead)
  f16*   Ktf  = (f16*)(w + (size_t)2 * 33554432); // R2
  f16*   Vtf  = (f16*)(w + (size_t)3 * 33554432); // R3
  f16*   W16  = (f16*)(w + (size_t)4 * 33554432); // R4
  f16*   EF16 = W16 + (size_t)4 * 1048576;        // R5
  f16*   KpVp = (f16*)(w + (size_t)4 * 33554432 + 8388608 + 4194304); // R6

  // 1. casts
  k_cast_x<<<16384, 256, 0, stream>>>(x, Xf);
  k_cast_w<<<6144, 256, 0, stream>>>(Wq, Wk, Wv, Wo, E, F, W16);

  // 2. projections: Q normal (16384x1024); K,V transposed (1024x16384)
  k_gemm<2, 2, false><<<dim3(8, 128), 256, 0, stream>>>(
      Xf, 1024, W16, 1024, 1024, nullptr, Qf, 1024, 1.f, bq, nullptr);
  k_gemm<2, 2, false><<<dim3(128, 8), 256, 0, stream>>>(
      W16 + 1048576, 1024, Xf, 1024, 1024, nullptr, Ktf, 16384, 1.f, nullptr, bk);
  k_gemm<2, 2, false><<<dim3(128, 8), 256, 0, stream>>>(
      W16 + 2 * 1048576, 1024, Xf, 1024, 1024, nullptr, Vtf, 16384, 1.f, nullptr, bv);

  // 3. low-rank projections with split-K=4 -> partials -> fp16
  k_lowrank<<<dim3(16, 1, 32), 256, 0, stream>>>(EF16, Ktf, Vtf, part);
  k_reduce<<<2048, 256, 0, stream>>>(part, KpVp);

  // 4. scores -> d_out attn region (fp32). Qf live; part dead after reduce.
  k_scores<<<dim3(2, 32, 64), 256, 0, stream>>>(Qf, KpVp, S);

  // 5. per-batch: softmax -> P (R0), then out_pre = P·Vp (R1; Qf dead now)
  for (int b = 0; b < 4; ++b) {
    k_softmax<<<16384, 256, 0, stream>>>(S + (size_t)b * 16 * 4096 * 256, Pf);
    k_pv<<<dim3(1, 32, 16), 128, 0, stream>>>(Pf, KpVp + (size_t)4 * 262144, OPf, b);
  }

  // 6. out = out_pre·Wo^T + bo
  k_gemm<2, 2, true><<<dim3(8, 128), 256, 0, stream>>>(
      OPf, 1024, W16 + 3 * 1048576, 1024, 1024, out, nullptr, 1024, 1.f, bo, nullptr);
}